// Round 17
// baseline (187.811 us; speedup 1.0000x reference)
//
#include <hip/hip_runtime.h>
#include <hip/hip_bf16.h>
#include <stdint.h>

// Q_Mlp: HAWQ-style quantized MLP on MI355X (gfx950).
// B=256, S=196 -> M=50176 rows. D=384, H=1536.
// Exact-integer int8 GEMMs via v_mfma_i32_16x16x64_i8, operands in 16x16-tiled
// layout (fragment = contiguous 1KB; staging source contiguous per wave; LDS
// in fragment order -> conflict-free ds_read_b128).
// Round 17: r16 base (186.8us verified). GEMM1 gains a 2-sub-phase split
// (extra mid-chunk s_barrier) + s_setprio(1) around each MFMA cluster (T5
// regime needs a phase split; m218b). GEMM2 + elementwise kernels untouched.

#define M_TOT 50176
#define D_IN  384
#define H_MID 1536
#define OUT_N (M_TOT * D_IN)
#define NSLOT 256
#define QW_BLOCKS (H_MID / 4 + D_IN / 4)   // 480 weight-quant blocks

typedef int v4i __attribute__((ext_vector_type(4)));

__device__ __forceinline__ float clamp_q(float q) {
  return fminf(fmaxf(q, -128.0f), 127.0f);
}

// near-correctly-rounded t/d given R = 1/d (IEEE): ~1 ulp.
__device__ __forceinline__ float fast_div(float t, float d, float R) {
  const float q1 = t * R;
  const float r  = fmaf(-d, q1, t);
  return fmaf(r, R, q1);
}

__device__ __forceinline__ void gld_lds16(const int8_t* g, int8_t* s) {
  __builtin_amdgcn_global_load_lds((const __attribute__((address_space(1))) void*)g,
                                   (__attribute__((address_space(3))) void*)s,
                                   16, 0, 0);
}

// Tiled int8 layout: addr(row,k) = (row>>4)*16*K + (k>>4)*256 + (row&15)*16 + (k&15)

// Merged quantization kernel:
//   blocks [0, H_MID/4)              : W1 rows (cols=384, with b1)
//   blocks [H_MID/4, QW_BLOCKS)      : W2 rows (cols=1536)
//   blocks [QW_BLOCKS, gridDim.x)    : x -> xq tiled (grid-stride wave tasks)
__global__ void quant_wx_kernel(const float* __restrict__ W1, const float* __restrict__ b1,
                                const float* __restrict__ W2, const float* __restrict__ x,
                                int8_t* __restrict__ W1q, int8_t* __restrict__ W2q,
                                int8_t* __restrict__ xq,
                                float* __restrict__ w1sf, float* __restrict__ w2sf,
                                int* __restrict__ b1i, const float* __restrict__ asf_p) {
  const int lane = threadIdx.x & 63;
  const int wid  = threadIdx.x >> 6;
  if (blockIdx.x < QW_BLOCKS) {
    const bool is1 = blockIdx.x < (H_MID / 4);
    const int row  = (is1 ? blockIdx.x : blockIdx.x - H_MID / 4) * 4 + wid;
    const int cols = is1 ? D_IN : H_MID;
    const float* wr = (is1 ? W1 : W2) + (size_t)row * cols;
    float m = 0.f;
    for (int c = lane; c < cols; c += 64) m = fmaxf(m, fabsf(wr[c]));
#pragma unroll
    for (int off = 32; off; off >>= 1) m = fmaxf(m, __shfl_xor(m, off));
    const float sf = m / 127.0f;            // matches jnp: max/QMAX (f32 division)
    int8_t* qbase = (is1 ? W1q : W2q) + (size_t)(row >> 4) * 16 * cols + (row & 15) * 16;
    for (int c = lane; c < cols; c += 64)
      qbase[(c >> 4) * 256 + (c & 15)] = (int8_t)clamp_q(rintf(wr[c] / sf));
    if (lane == 0) {
      if (is1) { w1sf[row] = sf; b1i[row] = (int)rintf(b1[row] / (sf * asf_p[0])); }
      else     { w2sf[row] = sf; }
    }
  } else {
    // x fake-quantized on asf grid -> rintf(x*R) == rintf(x/asf) exactly.
    const float R = 1.0f / asf_p[0];
    const int r  = lane & 15;
    const int kq = lane >> 4;
    const int bid    = blockIdx.x - QW_BLOCKS;
    const int nblk   = gridDim.x - QW_BLOCKS;
    const int ntask  = (M_TOT / 16) * 6;
    for (int task = bid * 4 + wid; task < ntask; task += nblk * 4) {
      const int pan = task / 6;
      const int kcq = task - pan * 6;
      const float* src = x + ((size_t)pan * 16 + r) * D_IN + (kcq * 4 + kq) * 16;
      int out[4];
#pragma unroll
      for (int q4 = 0; q4 < 4; ++q4) {
        float4 v = *(const float4*)(src + q4 * 4);
        unsigned a0 = (unsigned char)(signed char)clamp_q(rintf(v.x * R));
        unsigned a1 = (unsigned char)(signed char)clamp_q(rintf(v.y * R));
        unsigned a2 = (unsigned char)(signed char)clamp_q(rintf(v.z * R));
        unsigned a3 = (unsigned char)(signed char)clamp_q(rintf(v.w * R));
        out[q4] = (int)(a0 | (a1 << 8) | (a2 << 16) | (a3 << 24));
      }
      *(int4*)(xq + (size_t)pan * 6144 + kcq * 1024 + lane * 16) = *(int4*)out;
    }
  }
}

// GEMM1 (swapped: A=w1q rows=h, B=xq rows=m). Tile 128h x 256m, K=384,
// 512 threads = 8 waves (2x4), wave tile 64x64 = acc[4][4]. K-chunk 64,
// 2-buf LDS (sA 16KB + sB 32KB), counted vmcnt(3).
// NEW: each chunk's compute split into 2 sub-phases (mid s_barrier) with
// s_setprio(1) around the MFMA clusters — creates the wave role-split T5
// needs. Buffer hazards unchanged (mid-barrier is pure extra sync).
// MODE 0: global max(relu(h)) only.  MODE 1: store hq int8 (tiled [m][h]).
template <int MODE>
__global__ __launch_bounds__(512, 4) void gemm1_i8_kernel(
    const int8_t* __restrict__ A, const int8_t* __restrict__ Bm,
    const float* __restrict__ sfv, const int* __restrict__ bintv,
    const float* __restrict__ asf_p, const unsigned* __restrict__ gmax_in,
    int8_t* __restrict__ Cq, unsigned* __restrict__ gmax_out) {
  const int K = D_IN;
  __shared__ __align__(16) int8_t sA[2][8192];    // 8 rowblk x 1KB
  __shared__ __align__(16) int8_t sB[2][16384];   // 16 rowblk x 1KB
  const int tid    = threadIdx.x;
  const int lane   = tid & 63;
  const int wid    = tid >> 6;
  const int wr     = wid >> 2;      // 0,1  (A 64-row half)
  const int wc     = wid & 3;       // 0..3 (B 64-row quarter)
  const int tid16  = tid * 16;
  const int lane16 = lane * 16;
  const int l16    = lane & 15;
  const int r0     = (lane >> 4) * 4;
  // bijective XCD swizzle (grid 2352 divisible by 8)
  const int cpx = gridDim.x >> 3;
  const int wg  = (blockIdx.x & 7) * cpx + (blockIdx.x >> 3);
  const int bm = wg % (H_MID / 128);   // h-tile (inner: consecutive share xq panel)
  const int bn = wg / (H_MID / 128);   // m-tile (256 rows)

  // sf1 (MODE 1): hoisted above the K-loop — hides under prologue staging.
  float sf1 = 0.f;
  if (MODE == 1) {
    float m = fmaxf(fmaxf(__uint_as_float(gmax_in[lane]),
                          __uint_as_float(gmax_in[lane + 64])),
                    fmaxf(__uint_as_float(gmax_in[lane + 128]),
                          __uint_as_float(gmax_in[lane + 192])));
#pragma unroll
    for (int off = 32; off; off >>= 1) m = fmaxf(m, __shfl_xor(m, off));
    sf1 = m / 127.0f;
  }

  const int8_t* gA0 = A  + (size_t)(bm * 8)  * (16 * K);
  const int8_t* gB0 = Bm + (size_t)(bn * 16) * (16 * K);
  const int fA = tid16;                            // one A load / thread
  const int baseA = (fA >> 10) * 16 * K + (fA & 1023);
  int baseB[2];
#pragma unroll
  for (int l = 0; l < 2; ++l) {
    const int f = l * 8192 + tid16;
    baseB[l] = (f >> 10) * 16 * K + (f & 1023);
  }

  v4i acc[4][4] = {};
  const int niter = K >> 6;   // 6

  // prologue: stage chunk 0 (3 loads/thread)
  gld_lds16(gA0 + baseA, &sA[0][tid16]);
#pragma unroll
  for (int l = 0; l < 2; ++l) gld_lds16(gB0 + baseB[l], &sB[0][l * 8192 + tid16]);

  for (int c = 0; c < niter; ++c) {
    const int buf = c & 1;
    if (c + 1 < niter) {           // stage next chunk; wait only on current
      const int co = (c + 1) << 10;
      gld_lds16(gA0 + baseA + co, &sA[buf ^ 1][tid16]);
#pragma unroll
      for (int l = 0; l < 2; ++l)
        gld_lds16(gB0 + baseB[l] + co, &sB[buf ^ 1][l * 8192 + tid16]);
      asm volatile("s_waitcnt vmcnt(3)" ::: "memory");
    } else {
      asm volatile("s_waitcnt vmcnt(0)" ::: "memory");
    }
    __builtin_amdgcn_s_barrier();        // all waves' chunk-c loads landed
    __builtin_amdgcn_sched_barrier(0);
    // ---- sub-phase 1: 6 reads, 8 MFMAs (i = 0,1) ----
    v4i af[4], bf[4];
#pragma unroll
    for (int i = 0; i < 2; ++i)
      af[i] = *(const v4i*)&sA[buf][(wr * 4 + i) * 1024 + lane16];
#pragma unroll
    for (int j = 0; j < 4; ++j)
      bf[j] = *(const v4i*)&sB[buf][(wc * 4 + j) * 1024 + lane16];
    __builtin_amdgcn_s_setprio(1);
#pragma unroll
    for (int i = 0; i < 2; ++i)
#pragma unroll
      for (int j = 0; j < 4; ++j)
        acc[i][j] = __builtin_amdgcn_mfma_i32_16x16x64_i8(af[i], bf[j], acc[i][j], 0, 0, 0);
    __builtin_amdgcn_s_setprio(0);
    __builtin_amdgcn_sched_barrier(0);
    __builtin_amdgcn_s_barrier();        // mid-phase split (pure extra sync)
    // ---- sub-phase 2: 2 reads, 8 MFMAs (i = 2,3) ----
#pragma unroll
    for (int i = 2; i < 4; ++i)
      af[i] = *(const v4i*)&sA[buf][(wr * 4 + i) * 1024 + lane16];
    __builtin_amdgcn_s_setprio(1);
#pragma unroll
    for (int i = 2; i < 4; ++i)
#pragma unroll
      for (int j = 0; j < 4; ++j)
        acc[i][j] = __builtin_amdgcn_mfma_i32_16x16x64_i8(af[i], bf[j], acc[i][j], 0, 0, 0);
    __builtin_amdgcn_s_setprio(0);
    __builtin_amdgcn_sched_barrier(0);   // reads stay inside the barrier pair
    __builtin_amdgcn_s_barrier();        // reads consumed; buf reusable next iter
  }

  float lmax = 0.f;
  if (MODE == 0) {
    // rows=h, cols=m. max(relu(h)) = scale[h]*(max_m acc + bi[h]); lmax>=0.
    const float asf = asf_p[0];
#pragma unroll
    for (int i = 0; i < 4; ++i) {
      const int hbase = bm * 128 + wr * 64 + i * 16 + r0;
#pragma unroll
      for (int r = 0; r < 4; ++r) {
        int mi = acc[i][0][r];
#pragma unroll
        for (int j = 1; j < 4; ++j) mi = max(mi, acc[i][j][r]);
        const int h = hbase + r;
        lmax = fmaxf(lmax, (float)(mi + bintv[h]) * (sfv[h] * asf));
      }
    }
#pragma unroll
    for (int off = 32; off; off >>= 1) lmax = fmaxf(lmax, __shfl_xor(lmax, off));
    if (lane == 0) atomicMax(&gmax_out[(wg * 8 + wid) & (NSLOT - 1)], __float_as_uint(lmax));
  } else {
    const float asf = asf_p[0];
    const float R   = 1.0f / sf1;     // one IEEE div
    // Pack 4 consecutive h (reg dim) into one dword of tiled hq[m][h], K=1536.
#pragma unroll
    for (int i = 0; i < 4; ++i) {
      const int hbase = bm * 128 + wr * 64 + i * 16 + r0;
      const int htile = bm * 8 + wr * 4 + i;
      float ratio[4];
      int bi4[4];
#pragma unroll
      for (int r = 0; r < 4; ++r) {
        const int h = hbase + r;
        ratio[r] = fast_div(sfv[h] * asf, sf1, R);
        bi4[r]   = bintv[h];
      }
#pragma unroll
      for (int j = 0; j < 4; ++j) {
        const int mm = bn * 256 + wc * 64 + j * 16 + l16;
        unsigned d = 0;
#pragma unroll
        for (int r = 0; r < 4; ++r) {
          const float f = (float)(acc[i][j][r] + bi4[r]);
          const int q = (int)fminf(fmaxf(rintf(f * ratio[r]), 0.f), 127.f);
          d |= (unsigned)q << (8 * r);
        }
        *(unsigned*)(Cq + (size_t)(mm >> 4) * 24576 + htile * 256 + (mm & 15) * 16 + r0) = d;
      }
    }
  }
}

// GEMM2 (A=hq rows=m, B=w2q rows=d). Tile 128x128, K=1536, 4 waves (2x2),
// K-chunk 64, 2-buf LDS 32KB, counted vmcnt(4). r9/r11-verified structure
// (untouched: catalog m232 shows 8-phase null at 128²/4-wave; m190 setprio
// null on lockstep).
__global__ __launch_bounds__(256, 4) void gemm2_i8_kernel(
    const int8_t* __restrict__ A, const int8_t* __restrict__ Bm,
    const float* __restrict__ sfv, const float* __restrict__ bias,
    const unsigned* __restrict__ gmax_in,
    float* __restrict__ Cout, unsigned* __restrict__ gmax_out) {
  const int K = H_MID;
  __shared__ __align__(16) int8_t sA[2][8192];
  __shared__ __align__(16) int8_t sB[2][8192];
  const int tid    = threadIdx.x;
  const int lane   = tid & 63;
  const int wid    = tid >> 6;
  const int wr     = wid >> 1;
  const int wc     = wid & 1;
  const int tid16  = tid * 16;
  const int lane16 = lane * 16;
  const int l16    = lane & 15;
  const int r0     = (lane >> 4) * 4;
  const int cpx = gridDim.x >> 3;
  const int wg  = (blockIdx.x & 7) * cpx + (blockIdx.x >> 3);
  const int bm = wg / (D_IN / 128);   // m-tile (outer: consecutive share hq panel)
  const int bn = wg % (D_IN / 128);   // d-tile

  // sf1 hoisted above the K-loop (slots final after GEMM1 pass A).
  float m0 = fmaxf(fmaxf(__uint_as_float(gmax_in[lane]),
                         __uint_as_float(gmax_in[lane + 64])),
                   fmaxf(__uint_as_float(gmax_in[lane + 128]),
                         __uint_as_float(gmax_in[lane + 192])));
#pragma unroll
  for (int off = 32; off; off >>= 1) m0 = fmaxf(m0, __shfl_xor(m0, off));
  const float sf1 = m0 / 127.0f;

  const int8_t* gA0 = A  + (size_t)(bm * 8) * (16 * K);
  const int8_t* gB0 = Bm + (size_t)(bn * 8) * (16 * K);
  int base[2];
#pragma unroll
  for (int l = 0; l < 2; ++l) {
    const int f = l * 4096 + tid16;
    base[l] = (f >> 10) * 16 * K + (f & 1023);
  }

  v4i acc[4][4] = {};
  const int niter = K >> 6;   // 24

#pragma unroll
  for (int l = 0; l < 2; ++l) gld_lds16(gA0 + base[l], &sA[0][l * 4096 + tid16]);
#pragma unroll
  for (int l = 0; l < 2; ++l) gld_lds16(gB0 + base[l], &sB[0][l * 4096 + tid16]);

  for (int c = 0; c < niter; ++c) {
    const int buf = c & 1;
    if (c + 1 < niter) {
      const int co = (c + 1) << 10;
#pragma unroll
      for (int l = 0; l < 2; ++l)
        gld_lds16(gA0 + base[l] + co, &sA[buf ^ 1][l * 4096 + tid16]);
#pragma unroll
      for (int l = 0; l < 2; ++l)
        gld_lds16(gB0 + base[l] + co, &sB[buf ^ 1][l * 4096 + tid16]);
      asm volatile("s_waitcnt vmcnt(4)" ::: "memory");
    } else {
      asm volatile("s_waitcnt vmcnt(0)" ::: "memory");
    }
    __builtin_amdgcn_s_barrier();
    __builtin_amdgcn_sched_barrier(0);
    v4i af[4], bf[4];
#pragma unroll
    for (int i = 0; i < 4; ++i)
      af[i] = *(const v4i*)&sA[buf][(wr * 4 + i) * 1024 + lane16];
#pragma unroll
    for (int j = 0; j < 4; ++j)
      bf[j] = *(const v4i*)&sB[buf][(wc * 4 + j) * 1024 + lane16];
#pragma unroll
    for (int i = 0; i < 4; ++i)
#pragma unroll
      for (int j = 0; j < 4; ++j)
        acc[i][j] = __builtin_amdgcn_mfma_i32_16x16x64_i8(af[i], bf[j], acc[i][j], 0, 0, 0);
    __builtin_amdgcn_sched_barrier(0);
    __builtin_amdgcn_s_barrier();
  }

  float lmax = 0.f;
  // rows=m, cols=d. y_pre into Cout row-major + integer extremes for |max|.
#pragma unroll
  for (int j = 0; j < 4; ++j) {
    const int d = bn * 128 + wc * 64 + j * 16 + l16;
    const float scale = sfv[d] * sf1;
    const int bi = (int)rintf(bias[d] / scale);   // per-column, IEEE
    int mi = acc[0][j][0], mn = acc[0][j][0];
#pragma unroll
    for (int i = 0; i < 4; ++i) {
      const int row = bm * 128 + wr * 64 + i * 16 + r0;
#pragma unroll
      for (int r = 0; r < 4; ++r) {
        const int a = acc[i][j][r];
        mi = max(mi, a); mn = min(mn, a);
        Cout[(size_t)(row + r) * D_IN + d] = (float)(a + bi) * scale;
      }
    }
    lmax = fmaxf(lmax, fmaxf(fabsf((float)(mi + bi) * scale),
                             fabsf((float)(mn + bi) * scale)));
  }
#pragma unroll
  for (int off = 32; off; off >>= 1) lmax = fmaxf(lmax, __shfl_xor(lmax, off));
  if (lane == 0) atomicMax(&gmax_out[(wg * 4 + wid) & (NSLOT - 1)], __float_as_uint(lmax));
}

// In-place final per-tensor quantization of d_out (y_pre -> y), + asf2 scalar.
// Per-wave butterfly reduce of the slot array (no LDS broadcast, no barrier).
__global__ void final_quant_kernel(float* __restrict__ y, const unsigned* __restrict__ slots,
                                   int n4) {
  const int tid  = threadIdx.x;
  const int lane = tid & 63;
  float m = fmaxf(fmaxf(__uint_as_float(slots[lane]),
                        __uint_as_float(slots[lane + 64])),
                  fmaxf(__uint_as_float(slots[lane + 128]),
                        __uint_as_float(slots[lane + 192])));
#pragma unroll
  for (int off = 32; off; off >>= 1) m = fmaxf(m, __shfl_xor(m, off));
  const float asf2 = m / 127.0f;     // butterfly leaves max in ALL lanes
  const float R = 1.0f / asf2;
  float4* y4 = (float4*)y;
  const int stride = gridDim.x * blockDim.x;
  for (int i = blockIdx.x * blockDim.x + tid; i < n4; i += stride) {
    float4 v = y4[i];
    v.x = clamp_q(rintf(fast_div(v.x, asf2, R))) * asf2;
    v.y = clamp_q(rintf(fast_div(v.y, asf2, R))) * asf2;
    v.z = clamp_q(rintf(fast_div(v.z, asf2, R))) * asf2;
    v.w = clamp_q(rintf(fast_div(v.w, asf2, R))) * asf2;
    y4[i] = v;
  }
  if (blockIdx.x == 0 && tid == 0) y[(size_t)n4 * 4] = asf2;  // output 1: asf2
}

extern "C" void kernel_launch(void* const* d_in, const int* in_sizes, int n_in,
                              void* d_out, int out_size, void* d_ws, size_t ws_size,
                              hipStream_t stream) {
  const float* x   = (const float*)d_in[0];
  const float* W1  = (const float*)d_in[1];
  const float* b1  = (const float*)d_in[2];
  const float* W2  = (const float*)d_in[3];
  const float* b2  = (const float*)d_in[4];
  const float* asf = (const float*)d_in[5];

  char* ws = (char*)d_ws;
  unsigned* gmax1 = (unsigned*)ws;           // NSLOT slots: max(relu(h))
  unsigned* gmax2 = (unsigned*)(ws + 1024);  // NSLOT slots: max|y_pre|
  size_t off = 4096;
  int8_t* xq   = (int8_t*)(ws + off); off += (size_t)M_TOT * D_IN;   // 19.3 MB (tiled)
  int8_t* w1q  = (int8_t*)(ws + off); off += (size_t)H_MID * D_IN;   // tiled K=384
  float*  w1sf = (float*)(ws + off);  off += (size_t)H_MID * 4;
  int*    b1i  = (int*)(ws + off);    off += (size_t)H_MID * 4;
  int8_t* w2q  = (int8_t*)(ws + off); off += (size_t)D_IN * H_MID;   // tiled K=1536
  float*  w2sf = (float*)(ws + off);  off += (size_t)D_IN * 4;
  off = (off + 255) & ~(size_t)255;
  int8_t* hq   = (int8_t*)(ws + off); off += (size_t)M_TOT * H_MID;  // 77.1 MB (tiled)

  hipMemsetAsync(d_ws, 0, 4096, stream);  // zero both slot arrays every call

  // merged weight+activation quantization (480 W-blocks + 2048 x-blocks)
  quant_wx_kernel<<<QW_BLOCKS + 2048, 256, 0, stream>>>(
      W1, b1, W2, x, w1q, w2q, xq, w1sf, w2sf, b1i, asf);

  const int g1 = (H_MID / 128) * (M_TOT / 256);  // 12 * 196 = 2352 (div 8)
  const int g2 = (M_TOT / 128) * (D_IN / 128);   // 392 * 3  = 1176 (div 8)
  // GEMM1 pass A: max(relu(h)) only
  gemm1_i8_kernel<0><<<g1, 512, 0, stream>>>(
      w1q, xq, w1sf, b1i, asf, nullptr, nullptr, gmax1);
  // GEMM1 pass B: emit tiled int8 hq on the sf1 grid
  gemm1_i8_kernel<1><<<g1, 512, 0, stream>>>(
      w1q, xq, w1sf, b1i, asf, gmax1, hq, nullptr);
  // GEMM2: y_pre into d_out + slot max|y_pre|
  gemm2_i8_kernel<<<g2, 256, 0, stream>>>(
      hq, w2q, w2sf, b2, gmax1, (float*)d_out, gmax2);
  // final per-tensor quantization in place (+ asf2 scalar)
  final_quant_kernel<<<4096, 256, 0, stream>>>((float*)d_out, gmax2, OUT_N / 4);
}

// Round 18
// 186.774 us; speedup vs baseline: 1.0056x; 1.0056x over previous
//
#include <hip/hip_runtime.h>
#include <hip/hip_bf16.h>
#include <stdint.h>

// Q_Mlp: HAWQ-style quantized MLP on MI355X (gfx950).
// B=256, S=196 -> M=50176 rows. D=384, H=1536.
// Exact-integer int8 GEMMs via v_mfma_i32_16x16x64_i8, operands in 16x16-tiled
// layout (fragment = contiguous 1KB; staging source contiguous per wave; LDS
// in fragment order -> conflict-free ds_read_b128).
// Round 18: FINAL consolidation = r16 verbatim (best verified: 186.8us).
// r17's T5 phase-split was null (catalog-consistent: m232/m190); reverted.
// Structure-family plateau: 3 GEMM passes ~54-55us each (lockstep-residency
// bound, no pipe saturated) + ~21us required elementwise/scale passes.

#define M_TOT 50176
#define D_IN  384
#define H_MID 1536
#define OUT_N (M_TOT * D_IN)
#define NSLOT 256
#define QW_BLOCKS (H_MID / 4 + D_IN / 4)   // 480 weight-quant blocks

typedef int v4i __attribute__((ext_vector_type(4)));

__device__ __forceinline__ float clamp_q(float q) {
  return fminf(fmaxf(q, -128.0f), 127.0f);
}

// near-correctly-rounded t/d given R = 1/d (IEEE): ~1 ulp.
__device__ __forceinline__ float fast_div(float t, float d, float R) {
  const float q1 = t * R;
  const float r  = fmaf(-d, q1, t);
  return fmaf(r, R, q1);
}

__device__ __forceinline__ void gld_lds16(const int8_t* g, int8_t* s) {
  __builtin_amdgcn_global_load_lds((const __attribute__((address_space(1))) void*)g,
                                   (__attribute__((address_space(3))) void*)s,
                                   16, 0, 0);
}

// Tiled int8 layout: addr(row,k) = (row>>4)*16*K + (k>>4)*256 + (row&15)*16 + (k&15)

// Merged quantization kernel:
//   blocks [0, H_MID/4)              : W1 rows (cols=384, with b1)
//   blocks [H_MID/4, QW_BLOCKS)      : W2 rows (cols=1536)
//   blocks [QW_BLOCKS, gridDim.x)    : x -> xq tiled (grid-stride wave tasks)
__global__ void quant_wx_kernel(const float* __restrict__ W1, const float* __restrict__ b1,
                                const float* __restrict__ W2, const float* __restrict__ x,
                                int8_t* __restrict__ W1q, int8_t* __restrict__ W2q,
                                int8_t* __restrict__ xq,
                                float* __restrict__ w1sf, float* __restrict__ w2sf,
                                int* __restrict__ b1i, const float* __restrict__ asf_p) {
  const int lane = threadIdx.x & 63;
  const int wid  = threadIdx.x >> 6;
  if (blockIdx.x < QW_BLOCKS) {
    const bool is1 = blockIdx.x < (H_MID / 4);
    const int row  = (is1 ? blockIdx.x : blockIdx.x - H_MID / 4) * 4 + wid;
    const int cols = is1 ? D_IN : H_MID;
    const float* wr = (is1 ? W1 : W2) + (size_t)row * cols;
    float m = 0.f;
    for (int c = lane; c < cols; c += 64) m = fmaxf(m, fabsf(wr[c]));
#pragma unroll
    for (int off = 32; off; off >>= 1) m = fmaxf(m, __shfl_xor(m, off));
    const float sf = m / 127.0f;            // matches jnp: max/QMAX (f32 division)
    int8_t* qbase = (is1 ? W1q : W2q) + (size_t)(row >> 4) * 16 * cols + (row & 15) * 16;
    for (int c = lane; c < cols; c += 64)
      qbase[(c >> 4) * 256 + (c & 15)] = (int8_t)clamp_q(rintf(wr[c] / sf));
    if (lane == 0) {
      if (is1) { w1sf[row] = sf; b1i[row] = (int)rintf(b1[row] / (sf * asf_p[0])); }
      else     { w2sf[row] = sf; }
    }
  } else {
    // x fake-quantized on asf grid -> rintf(x*R) == rintf(x/asf) exactly.
    const float R = 1.0f / asf_p[0];
    const int r  = lane & 15;
    const int kq = lane >> 4;
    const int bid    = blockIdx.x - QW_BLOCKS;
    const int nblk   = gridDim.x - QW_BLOCKS;
    const int ntask  = (M_TOT / 16) * 6;
    for (int task = bid * 4 + wid; task < ntask; task += nblk * 4) {
      const int pan = task / 6;
      const int kcq = task - pan * 6;
      const float* src = x + ((size_t)pan * 16 + r) * D_IN + (kcq * 4 + kq) * 16;
      int out[4];
#pragma unroll
      for (int q4 = 0; q4 < 4; ++q4) {
        float4 v = *(const float4*)(src + q4 * 4);
        unsigned a0 = (unsigned char)(signed char)clamp_q(rintf(v.x * R));
        unsigned a1 = (unsigned char)(signed char)clamp_q(rintf(v.y * R));
        unsigned a2 = (unsigned char)(signed char)clamp_q(rintf(v.z * R));
        unsigned a3 = (unsigned char)(signed char)clamp_q(rintf(v.w * R));
        out[q4] = (int)(a0 | (a1 << 8) | (a2 << 16) | (a3 << 24));
      }
      *(int4*)(xq + (size_t)pan * 6144 + kcq * 1024 + lane * 16) = *(int4*)out;
    }
  }
}

// GEMM1 (swapped: A=w1q rows=h, B=xq rows=m). Tile 128h x 256m, K=384,
// 512 threads = 8 waves (2x4), wave tile 64x64 = acc[4][4]. K-chunk 64,
// 2-buf LDS (sA 16KB + sB 32KB), counted vmcnt(3) (3 staging loads/thread).
// MODE 0: global max(relu(h)) only.  MODE 1: store hq int8 (tiled [m][h]).
template <int MODE>
__global__ __launch_bounds__(512, 4) void gemm1_i8_kernel(
    const int8_t* __restrict__ A, const int8_t* __restrict__ Bm,
    const float* __restrict__ sfv, const int* __restrict__ bintv,
    const float* __restrict__ asf_p, const unsigned* __restrict__ gmax_in,
    int8_t* __restrict__ Cq, unsigned* __restrict__ gmax_out) {
  const int K = D_IN;
  __shared__ __align__(16) int8_t sA[2][8192];    // 8 rowblk x 1KB
  __shared__ __align__(16) int8_t sB[2][16384];   // 16 rowblk x 1KB
  const int tid    = threadIdx.x;
  const int lane   = tid & 63;
  const int wid    = tid >> 6;
  const int wr     = wid >> 2;      // 0,1  (A 64-row half)
  const int wc     = wid & 3;       // 0..3 (B 64-row quarter)
  const int tid16  = tid * 16;
  const int lane16 = lane * 16;
  const int l16    = lane & 15;
  const int r0     = (lane >> 4) * 4;
  // bijective XCD swizzle (grid 2352 divisible by 8)
  const int cpx = gridDim.x >> 3;
  const int wg  = (blockIdx.x & 7) * cpx + (blockIdx.x >> 3);
  const int bm = wg % (H_MID / 128);   // h-tile (inner: consecutive share xq panel)
  const int bn = wg / (H_MID / 128);   // m-tile (256 rows)

  // sf1 (MODE 1): hoisted above the K-loop — hides under prologue staging.
  float sf1 = 0.f;
  if (MODE == 1) {
    float m = fmaxf(fmaxf(__uint_as_float(gmax_in[lane]),
                          __uint_as_float(gmax_in[lane + 64])),
                    fmaxf(__uint_as_float(gmax_in[lane + 128]),
                          __uint_as_float(gmax_in[lane + 192])));
#pragma unroll
    for (int off = 32; off; off >>= 1) m = fmaxf(m, __shfl_xor(m, off));
    sf1 = m / 127.0f;
  }

  const int8_t* gA0 = A  + (size_t)(bm * 8)  * (16 * K);
  const int8_t* gB0 = Bm + (size_t)(bn * 16) * (16 * K);
  const int fA = tid16;                            // one A load / thread
  const int baseA = (fA >> 10) * 16 * K + (fA & 1023);
  int baseB[2];
#pragma unroll
  for (int l = 0; l < 2; ++l) {
    const int f = l * 8192 + tid16;
    baseB[l] = (f >> 10) * 16 * K + (f & 1023);
  }

  v4i acc[4][4] = {};
  const int niter = K >> 6;   // 6

  // prologue: stage chunk 0 (3 loads/thread)
  gld_lds16(gA0 + baseA, &sA[0][tid16]);
#pragma unroll
  for (int l = 0; l < 2; ++l) gld_lds16(gB0 + baseB[l], &sB[0][l * 8192 + tid16]);

  for (int c = 0; c < niter; ++c) {
    const int buf = c & 1;
    if (c + 1 < niter) {           // stage next chunk; wait only on current
      const int co = (c + 1) << 10;
      gld_lds16(gA0 + baseA + co, &sA[buf ^ 1][tid16]);
#pragma unroll
      for (int l = 0; l < 2; ++l)
        gld_lds16(gB0 + baseB[l] + co, &sB[buf ^ 1][l * 8192 + tid16]);
      asm volatile("s_waitcnt vmcnt(3)" ::: "memory");
    } else {
      asm volatile("s_waitcnt vmcnt(0)" ::: "memory");
    }
    __builtin_amdgcn_s_barrier();        // all waves' chunk-c loads landed
    __builtin_amdgcn_sched_barrier(0);
    v4i af[4], bf[4];
#pragma unroll
    for (int i = 0; i < 4; ++i)
      af[i] = *(const v4i*)&sA[buf][(wr * 4 + i) * 1024 + lane16];
#pragma unroll
    for (int j = 0; j < 4; ++j)
      bf[j] = *(const v4i*)&sB[buf][(wc * 4 + j) * 1024 + lane16];
#pragma unroll
    for (int i = 0; i < 4; ++i)
#pragma unroll
      for (int j = 0; j < 4; ++j)
        acc[i][j] = __builtin_amdgcn_mfma_i32_16x16x64_i8(af[i], bf[j], acc[i][j], 0, 0, 0);
    __builtin_amdgcn_sched_barrier(0);   // reads stay inside the barrier pair
    __builtin_amdgcn_s_barrier();        // reads consumed; buf reusable next iter
  }

  float lmax = 0.f;
  if (MODE == 0) {
    // rows=h, cols=m. max(relu(h)) = scale[h]*(max_m acc + bi[h]); lmax>=0.
    const float asf = asf_p[0];
#pragma unroll
    for (int i = 0; i < 4; ++i) {
      const int hbase = bm * 128 + wr * 64 + i * 16 + r0;
#pragma unroll
      for (int r = 0; r < 4; ++r) {
        int mi = acc[i][0][r];
#pragma unroll
        for (int j = 1; j < 4; ++j) mi = max(mi, acc[i][j][r]);
        const int h = hbase + r;
        lmax = fmaxf(lmax, (float)(mi + bintv[h]) * (sfv[h] * asf));
      }
    }
#pragma unroll
    for (int off = 32; off; off >>= 1) lmax = fmaxf(lmax, __shfl_xor(lmax, off));
    if (lane == 0) atomicMax(&gmax_out[(wg * 8 + wid) & (NSLOT - 1)], __float_as_uint(lmax));
  } else {
    const float asf = asf_p[0];
    const float R   = 1.0f / sf1;     // one IEEE div
    // Pack 4 consecutive h (reg dim) into one dword of tiled hq[m][h], K=1536.
#pragma unroll
    for (int i = 0; i < 4; ++i) {
      const int hbase = bm * 128 + wr * 64 + i * 16 + r0;
      const int htile = bm * 8 + wr * 4 + i;
      float ratio[4];
      int bi4[4];
#pragma unroll
      for (int r = 0; r < 4; ++r) {
        const int h = hbase + r;
        ratio[r] = fast_div(sfv[h] * asf, sf1, R);
        bi4[r]   = bintv[h];
      }
#pragma unroll
      for (int j = 0; j < 4; ++j) {
        const int mm = bn * 256 + wc * 64 + j * 16 + l16;
        unsigned d = 0;
#pragma unroll
        for (int r = 0; r < 4; ++r) {
          const float f = (float)(acc[i][j][r] + bi4[r]);
          const int q = (int)fminf(fmaxf(rintf(f * ratio[r]), 0.f), 127.f);
          d |= (unsigned)q << (8 * r);
        }
        *(unsigned*)(Cq + (size_t)(mm >> 4) * 24576 + htile * 256 + (mm & 15) * 16 + r0) = d;
      }
    }
  }
}

// GEMM2 (A=hq rows=m, B=w2q rows=d). Tile 128x128, K=1536, 4 waves (2x2),
// K-chunk 64, 2-buf LDS 32KB, counted vmcnt(4). r9/r11-verified structure.
__global__ __launch_bounds__(256, 4) void gemm2_i8_kernel(
    const int8_t* __restrict__ A, const int8_t* __restrict__ Bm,
    const float* __restrict__ sfv, const float* __restrict__ bias,
    const unsigned* __restrict__ gmax_in,
    float* __restrict__ Cout, unsigned* __restrict__ gmax_out) {
  const int K = H_MID;
  __shared__ __align__(16) int8_t sA[2][8192];
  __shared__ __align__(16) int8_t sB[2][8192];
  const int tid    = threadIdx.x;
  const int lane   = tid & 63;
  const int wid    = tid >> 6;
  const int wr     = wid >> 1;
  const int wc     = wid & 1;
  const int tid16  = tid * 16;
  const int lane16 = lane * 16;
  const int l16    = lane & 15;
  const int r0     = (lane >> 4) * 4;
  const int cpx = gridDim.x >> 3;
  const int wg  = (blockIdx.x & 7) * cpx + (blockIdx.x >> 3);
  const int bm = wg / (D_IN / 128);   // m-tile (outer: consecutive share hq panel)
  const int bn = wg % (D_IN / 128);   // d-tile

  // sf1 hoisted above the K-loop (slots final after GEMM1 pass A).
  float m0 = fmaxf(fmaxf(__uint_as_float(gmax_in[lane]),
                         __uint_as_float(gmax_in[lane + 64])),
                   fmaxf(__uint_as_float(gmax_in[lane + 128]),
                         __uint_as_float(gmax_in[lane + 192])));
#pragma unroll
  for (int off = 32; off; off >>= 1) m0 = fmaxf(m0, __shfl_xor(m0, off));
  const float sf1 = m0 / 127.0f;

  const int8_t* gA0 = A  + (size_t)(bm * 8) * (16 * K);
  const int8_t* gB0 = Bm + (size_t)(bn * 8) * (16 * K);
  int base[2];
#pragma unroll
  for (int l = 0; l < 2; ++l) {
    const int f = l * 4096 + tid16;
    base[l] = (f >> 10) * 16 * K + (f & 1023);
  }

  v4i acc[4][4] = {};
  const int niter = K >> 6;   // 24

#pragma unroll
  for (int l = 0; l < 2; ++l) gld_lds16(gA0 + base[l], &sA[0][l * 4096 + tid16]);
#pragma unroll
  for (int l = 0; l < 2; ++l) gld_lds16(gB0 + base[l], &sB[0][l * 4096 + tid16]);

  for (int c = 0; c < niter; ++c) {
    const int buf = c & 1;
    if (c + 1 < niter) {
      const int co = (c + 1) << 10;
#pragma unroll
      for (int l = 0; l < 2; ++l)
        gld_lds16(gA0 + base[l] + co, &sA[buf ^ 1][l * 4096 + tid16]);
#pragma unroll
      for (int l = 0; l < 2; ++l)
        gld_lds16(gB0 + base[l] + co, &sB[buf ^ 1][l * 4096 + tid16]);
      asm volatile("s_waitcnt vmcnt(4)" ::: "memory");
    } else {
      asm volatile("s_waitcnt vmcnt(0)" ::: "memory");
    }
    __builtin_amdgcn_s_barrier();
    __builtin_amdgcn_sched_barrier(0);
    v4i af[4], bf[4];
#pragma unroll
    for (int i = 0; i < 4; ++i)
      af[i] = *(const v4i*)&sA[buf][(wr * 4 + i) * 1024 + lane16];
#pragma unroll
    for (int j = 0; j < 4; ++j)
      bf[j] = *(const v4i*)&sB[buf][(wc * 4 + j) * 1024 + lane16];
#pragma unroll
    for (int i = 0; i < 4; ++i)
#pragma unroll
      for (int j = 0; j < 4; ++j)
        acc[i][j] = __builtin_amdgcn_mfma_i32_16x16x64_i8(af[i], bf[j], acc[i][j], 0, 0, 0);
    __builtin_amdgcn_sched_barrier(0);
    __builtin_amdgcn_s_barrier();
  }

  float lmax = 0.f;
  // rows=m, cols=d. y_pre into Cout row-major + integer extremes for |max|.
#pragma unroll
  for (int j = 0; j < 4; ++j) {
    const int d = bn * 128 + wc * 64 + j * 16 + l16;
    const float scale = sfv[d] * sf1;
    const int bi = (int)rintf(bias[d] / scale);   // per-column, IEEE
    int mi = acc[0][j][0], mn = acc[0][j][0];
#pragma unroll
    for (int i = 0; i < 4; ++i) {
      const int row = bm * 128 + wr * 64 + i * 16 + r0;
#pragma unroll
      for (int r = 0; r < 4; ++r) {
        const int a = acc[i][j][r];
        mi = max(mi, a); mn = min(mn, a);
        Cout[(size_t)(row + r) * D_IN + d] = (float)(a + bi) * scale;
      }
    }
    lmax = fmaxf(lmax, fmaxf(fabsf((float)(mi + bi) * scale),
                             fabsf((float)(mn + bi) * scale)));
  }
#pragma unroll
  for (int off = 32; off; off >>= 1) lmax = fmaxf(lmax, __shfl_xor(lmax, off));
  if (lane == 0) atomicMax(&gmax_out[(wg * 4 + wid) & (NSLOT - 1)], __float_as_uint(lmax));
}

// In-place final per-tensor quantization of d_out (y_pre -> y), + asf2 scalar.
// Per-wave butterfly reduce of the slot array (no LDS broadcast, no barrier).
__global__ void final_quant_kernel(float* __restrict__ y, const unsigned* __restrict__ slots,
                                   int n4) {
  const int tid  = threadIdx.x;
  const int lane = tid & 63;
  float m = fmaxf(fmaxf(__uint_as_float(slots[lane]),
                        __uint_as_float(slots[lane + 64])),
                  fmaxf(__uint_as_float(slots[lane + 128]),
                        __uint_as_float(slots[lane + 192])));
#pragma unroll
  for (int off = 32; off; off >>= 1) m = fmaxf(m, __shfl_xor(m, off));
  const float asf2 = m / 127.0f;     // butterfly leaves max in ALL lanes
  const float R = 1.0f / asf2;
  float4* y4 = (float4*)y;
  const int stride = gridDim.x * blockDim.x;
  for (int i = blockIdx.x * blockDim.x + tid; i < n4; i += stride) {
    float4 v = y4[i];
    v.x = clamp_q(rintf(fast_div(v.x, asf2, R))) * asf2;
    v.y = clamp_q(rintf(fast_div(v.y, asf2, R))) * asf2;
    v.z = clamp_q(rintf(fast_div(v.z, asf2, R))) * asf2;
    v.w = clamp_q(rintf(fast_div(v.w, asf2, R))) * asf2;
    y4[i] = v;
  }
  if (blockIdx.x == 0 && tid == 0) y[(size_t)n4 * 4] = asf2;  // output 1: asf2
}

extern "C" void kernel_launch(void* const* d_in, const int* in_sizes, int n_in,
                              void* d_out, int out_size, void* d_ws, size_t ws_size,
                              hipStream_t stream) {
  const float* x   = (const float*)d_in[0];
  const float* W1  = (const float*)d_in[1];
  const float* b1  = (const float*)d_in[2];
  const float* W2  = (const float*)d_in[3];
  const float* b2  = (const float*)d_in[4];
  const float* asf = (const float*)d_in[5];

  char* ws = (char*)d_ws;
  unsigned* gmax1 = (unsigned*)ws;           // NSLOT slots: max(relu(h))
  unsigned* gmax2 = (unsigned*)(ws + 1024);  // NSLOT slots: max|y_pre|
  size_t off = 4096;
  int8_t* xq   = (int8_t*)(ws + off); off += (size_t)M_TOT * D_IN;   // 19.3 MB (tiled)
  int8_t* w1q  = (int8_t*)(ws + off); off += (size_t)H_MID * D_IN;   // tiled K=384
  float*  w1sf = (float*)(ws + off);  off += (size_t)H_MID * 4;
  int*    b1i  = (int*)(ws + off);    off += (size_t)H_MID * 4;
  int8_t* w2q  = (int8_t*)(ws + off); off += (size_t)D_IN * H_MID;   // tiled K=1536
  float*  w2sf = (float*)(ws + off);  off += (size_t)D_IN * 4;
  off = (off + 255) & ~(size_t)255;
  int8_t* hq   = (int8_t*)(ws + off); off += (size_t)M_TOT * H_MID;  // 77.1 MB (tiled)

  hipMemsetAsync(d_ws, 0, 4096, stream);  // zero both slot arrays every call

  // merged weight+activation quantization (480 W-blocks + 2048 x-blocks)
  quant_wx_kernel<<<QW_BLOCKS + 2048, 256, 0, stream>>>(
      W1, b1, W2, x, w1q, w2q, xq, w1sf, w2sf, b1i, asf);

  const int g1 = (H_MID / 128) * (M_TOT / 256);  // 12 * 196 = 2352 (div 8)
  const int g2 = (M_TOT / 128) * (D_IN / 128);   // 392 * 3  = 1176 (div 8)
  // GEMM1 pass A: max(relu(h)) only
  gemm1_i8_kernel<0><<<g1, 512, 0, stream>>>(
      w1q, xq, w1sf, b1i, asf, nullptr, nullptr, gmax1);
  // GEMM1 pass B: emit tiled int8 hq on the sf1 grid
  gemm1_i8_kernel<1><<<g1, 512, 0, stream>>>(
      w1q, xq, w1sf, b1i, asf, gmax1, hq, nullptr);
  // GEMM2: y_pre into d_out + slot max|y_pre|
  gemm2_i8_kernel<<<g2, 256, 0, stream>>>(
      hq, w2q, w2sf, b2, gmax1, (float*)d_out, gmax2);
  // final per-tensor quantization in place (+ asf2 scalar)
  final_quant_kernel<<<4096, 256, 0, stream>>>((float*)d_out, gmax2, OUT_N / 4);
}